// Round 2
// baseline (453.160 us; speedup 1.0000x reference)
//
#include <hip/hip_runtime.h>
#include <hip/hip_bf16.h>

// Problem constants
#define B_DIM 64
#define S_DIM 128
#define D1    256
#define D2    256
#define KTOT  65536   // D1*D2
#define NOUT  1024

#define KSPLIT 128
#define KCHUNK (KTOT / KSPLIT)   // 512 -> 16 MFMA k-iters of 32 per block
#define KITERS (KCHUNK / 32)

typedef __attribute__((ext_vector_type(8))) short bf16x8;
typedef __attribute__((ext_vector_type(4))) float f32x4;

// Pack two fp32 -> two bf16 (round-half-up; ~2.5 VALU ops/elem)
__device__ inline unsigned pack2bf16(float lo, float hi) {
    unsigned ulo = __float_as_uint(lo);
    unsigned uhi = __float_as_uint(hi);
    ulo = (ulo + 0x8000u) >> 16;
    uhi = (uhi + 0x8000u) & 0xffff0000u;
    return ulo | uhi;
}

// ---------------------------------------------------------------------------
// tp[b, d*256+e] = sum_s ftab[fillers[b,s], d] * rtab[roles[b,s], e]  (bf16)
__global__ __launch_bounds__(256) void tp_kernel(const int* __restrict__ fillers,
                                                 const int* __restrict__ roles,
                                                 const float* __restrict__ ftab,
                                                 const float* __restrict__ rtab,
                                                 unsigned short* __restrict__ tp) {
    const int b     = blockIdx.x;        // 0..63
    const int dbase = blockIdx.y * 32;   // 8 tiles of 32
    __shared__ float f_sh[S_DIM][32];
    __shared__ int   ridx[S_DIM];
    const int t = threadIdx.x;

    const int* fb = fillers + b * S_DIM;
    for (int i = t; i < S_DIM * 32; i += 256) {
        int s = i >> 5, dl = i & 31;
        f_sh[s][dl] = ftab[(long)fb[s] * D1 + dbase + dl];
    }
    if (t < S_DIM) ridx[t] = roles[b * S_DIM + t];
    __syncthreads();

    const int dsub = t >> 6;   // wave-uniform: d = dbase + dsub*8 + dl
    const int et   = t & 63;   // e = et*4
    float acc[8][4];
#pragma unroll
    for (int i = 0; i < 8; ++i)
#pragma unroll
        for (int j = 0; j < 4; ++j) acc[i][j] = 0.f;

    for (int s = 0; s < S_DIM; ++s) {
        const float4 rv = *(const float4*)(rtab + ridx[s] * D2 + et * 4);
        const float4 f0 = *(const float4*)&f_sh[s][dsub * 8];
        const float4 f1 = *(const float4*)&f_sh[s][dsub * 8 + 4];
        float fv[8] = {f0.x, f0.y, f0.z, f0.w, f1.x, f1.y, f1.z, f1.w};
        float rr[4] = {rv.x, rv.y, rv.z, rv.w};
#pragma unroll
        for (int dl = 0; dl < 8; ++dl)
#pragma unroll
            for (int c = 0; c < 4; ++c) acc[dl][c] += fv[dl] * rr[c];
    }

    unsigned short* dst = tp + (size_t)b * KTOT + (size_t)(dbase + dsub * 8) * D2 + et * 4;
#pragma unroll
    for (int dl = 0; dl < 8; ++dl) {
        uint2 pp;
        pp.x = pack2bf16(acc[dl][0], acc[dl][1]);
        pp.y = pack2bf16(acc[dl][2], acc[dl][3]);
        *(uint2*)(dst + (size_t)dl * D2) = pp;
    }
}

// ---------------------------------------------------------------------------
// part[ks][64][1024] = tp[64, kchunk](bf16) @ W[1024, kchunk]^T   (plain stores,
// no atomics). Grid: 16 n-tiles x 128 k-splits. Each wave: 16 cols x 64 rows.
// 1-deep register prefetch: load k-iter+1 while packing/MFMAing k-iter.
__global__ __launch_bounds__(256) void gemm_kernel(const unsigned short* __restrict__ tp,
                                                   const float* __restrict__ W,
                                                   float* __restrict__ part) {
    const int nt  = blockIdx.x;            // 0..15
    const int ks  = blockIdx.y;            // 0..KSPLIT-1
    const int w   = threadIdx.x >> 6;      // wave 0..3
    const int L   = threadIdx.x & 63;
    const int l16 = L & 15;
    const int lq  = L >> 4;                // 0..3 (k-quad)
    const int ncol = nt * 64 + w * 16;
    const int k0   = ks * KCHUNK + lq * 8;

    const unsigned short* tpp = tp + (size_t)l16 * KTOT + k0;      // A[m=l16][k]
    const float*          wp  = W + (size_t)(ncol + l16) * KTOT + k0; // B[k][n=l16]

    f32x4 acc[4];
#pragma unroll
    for (int mt = 0; mt < 4; ++mt) acc[mt] = (f32x4){0.f, 0.f, 0.f, 0.f};

    bf16x8 ca0 = *(const bf16x8*)(tpp);
    bf16x8 ca1 = *(const bf16x8*)(tpp + 16 * KTOT);
    bf16x8 ca2 = *(const bf16x8*)(tpp + 32 * KTOT);
    bf16x8 ca3 = *(const bf16x8*)(tpp + 48 * KTOT);
    float4 cw0 = *(const float4*)(wp);
    float4 cw1 = *(const float4*)(wp + 4);

#pragma unroll
    for (int kk = 0; kk < KITERS; ++kk) {
        bf16x8 na0, na1, na2, na3;
        float4 nw0, nw1;
        if (kk + 1 < KITERS) {
            const unsigned short* tn = tpp + (kk + 1) * 32;
            const float*          wn = wp + (kk + 1) * 32;
            na0 = *(const bf16x8*)(tn);
            na1 = *(const bf16x8*)(tn + 16 * KTOT);
            na2 = *(const bf16x8*)(tn + 32 * KTOT);
            na3 = *(const bf16x8*)(tn + 48 * KTOT);
            nw0 = *(const float4*)(wn);
            nw1 = *(const float4*)(wn + 4);
        }
        int4 pb;
        pb.x = (int)pack2bf16(cw0.x, cw0.y);
        pb.y = (int)pack2bf16(cw0.z, cw0.w);
        pb.z = (int)pack2bf16(cw1.x, cw1.y);
        pb.w = (int)pack2bf16(cw1.z, cw1.w);
        bf16x8 bw = *(bf16x8*)&pb;
        acc[0] = __builtin_amdgcn_mfma_f32_16x16x32_bf16(ca0, bw, acc[0], 0, 0, 0);
        acc[1] = __builtin_amdgcn_mfma_f32_16x16x32_bf16(ca1, bw, acc[1], 0, 0, 0);
        acc[2] = __builtin_amdgcn_mfma_f32_16x16x32_bf16(ca2, bw, acc[2], 0, 0, 0);
        acc[3] = __builtin_amdgcn_mfma_f32_16x16x32_bf16(ca3, bw, acc[3], 0, 0, 0);
        ca0 = na0; ca1 = na1; ca2 = na2; ca3 = na3;
        cw0 = nw0; cw1 = nw1;
    }

    // D[row = mt*16 + lq*4 + r][col = ncol + l16], one plain store each.
    float* pp = part + (size_t)ks * (B_DIM * NOUT) + ncol + l16;
#pragma unroll
    for (int mt = 0; mt < 4; ++mt)
#pragma unroll
        for (int r = 0; r < 4; ++r)
            pp[(size_t)(mt * 16 + lq * 4 + r) * NOUT] = acc[mt][r];
}

// ---------------------------------------------------------------------------
// out[m][n] = bias[n] + sum_ks part[ks][m][n].  16384 threads, float4 each.
__global__ __launch_bounds__(256) void reduce_kernel(const float* __restrict__ part,
                                                     const float* __restrict__ bias,
                                                     float* __restrict__ out) {
    const int i    = blockIdx.x * 256 + threadIdx.x;   // 0..16383
    const size_t o = (size_t)i * 4;
    const float* p = part + o;
    f32x4 a0 = {0.f, 0.f, 0.f, 0.f};
    f32x4 a1 = {0.f, 0.f, 0.f, 0.f};
#pragma unroll 8
    for (int ks = 0; ks < KSPLIT; ks += 2) {
        f32x4 x = *(const f32x4*)(p + (size_t)ks * (B_DIM * NOUT));
        f32x4 y = *(const f32x4*)(p + (size_t)(ks + 1) * (B_DIM * NOUT));
        a0 += x;
        a1 += y;
    }
    f32x4 bv = *(const f32x4*)(bias + (o & (NOUT - 1)));
    f32x4 r  = a0 + a1 + bv;
    *(f32x4*)(out + o) = r;
}

// ---------------------------------------------------------------------------
extern "C" void kernel_launch(void* const* d_in, const int* in_sizes, int n_in,
                              void* d_out, int out_size, void* d_ws, size_t ws_size,
                              hipStream_t stream) {
    const int*   fillers = (const int*)d_in[0];
    const int*   roles   = (const int*)d_in[1];
    const float* ftab    = (const float*)d_in[2];
    const float* rtab    = (const float*)d_in[3];
    const float* W       = (const float*)d_in[4];
    const float* bias    = (const float*)d_in[5];
    float* out = (float*)d_out;

    float*          part = (float*)d_ws;                       // 128*64*1024*4 = 32 MB
    unsigned short* tp   = (unsigned short*)((char*)d_ws + (size_t)KSPLIT * B_DIM * NOUT * 4); // 8 MB

    hipLaunchKernelGGL(tp_kernel, dim3(B_DIM, 8), dim3(256), 0, stream,
                       fillers, roles, ftab, rtab, tp);
    hipLaunchKernelGGL(gemm_kernel, dim3(16, KSPLIT), dim3(256), 0, stream, tp, W, part);
    hipLaunchKernelGGL(reduce_kernel, dim3(64), dim3(256), 0, stream, part, bias, out);
}

// Round 3
// 445.567 us; speedup vs baseline: 1.0170x; 1.0170x over previous
//
#include <hip/hip_runtime.h>
#include <hip/hip_bf16.h>

// Problem constants
#define B_DIM 64
#define S_DIM 128
#define D1    256
#define D2    256
#define KTOT  65536   // D1*D2
#define NOUT  1024

#define KSPLIT 64
#define KCHUNK (KTOT / KSPLIT)   // 1024 k per block
#define BK     128               // k per staging tile
#define BKITERS (KCHUNK / BK)    // 8
#define KSTEPS  (BK / 32)        // 4 mfma k-steps per staging tile
#define WPAD   16                // bf16 pad per LDS row (spreads banks)

typedef __attribute__((ext_vector_type(8))) short bf16x8;
typedef __attribute__((ext_vector_type(4))) float f32x4;

// Pack two fp32 -> two bf16 (round-half-up)
__device__ inline unsigned pack2bf16(float lo, float hi) {
    unsigned ulo = __float_as_uint(lo);
    unsigned uhi = __float_as_uint(hi);
    ulo = (ulo + 0x8000u) >> 16;
    uhi = (uhi + 0x8000u) & 0xffff0000u;
    return ulo | uhi;
}

// ---------------------------------------------------------------------------
// tp[b, d*256+e] = sum_s ftab[fillers[b,s], d] * rtab[roles[b,s], e]  (bf16)
__global__ __launch_bounds__(256) void tp_kernel(const int* __restrict__ fillers,
                                                 const int* __restrict__ roles,
                                                 const float* __restrict__ ftab,
                                                 const float* __restrict__ rtab,
                                                 unsigned short* __restrict__ tp) {
    const int b     = blockIdx.x;        // 0..63
    const int dbase = blockIdx.y * 32;   // 8 tiles of 32
    __shared__ float f_sh[S_DIM][32];
    __shared__ int   ridx[S_DIM];
    const int t = threadIdx.x;

    const int* fb = fillers + b * S_DIM;
    for (int i = t; i < S_DIM * 32; i += 256) {
        int s = i >> 5, dl = i & 31;
        f_sh[s][dl] = ftab[(long)fb[s] * D1 + dbase + dl];
    }
    if (t < S_DIM) ridx[t] = roles[b * S_DIM + t];
    __syncthreads();

    const int dsub = t >> 6;   // wave-uniform: d = dbase + dsub*8 + dl
    const int et   = t & 63;   // e = et*4
    float acc[8][4];
#pragma unroll
    for (int i = 0; i < 8; ++i)
#pragma unroll
        for (int j = 0; j < 4; ++j) acc[i][j] = 0.f;

    for (int s = 0; s < S_DIM; ++s) {
        const float4 rv = *(const float4*)(rtab + ridx[s] * D2 + et * 4);
        const float4 f0 = *(const float4*)&f_sh[s][dsub * 8];
        const float4 f1 = *(const float4*)&f_sh[s][dsub * 8 + 4];
        float fv[8] = {f0.x, f0.y, f0.z, f0.w, f1.x, f1.y, f1.z, f1.w};
        float rr[4] = {rv.x, rv.y, rv.z, rv.w};
#pragma unroll
        for (int dl = 0; dl < 8; ++dl)
#pragma unroll
            for (int c = 0; c < 4; ++c) acc[dl][c] += fv[dl] * rr[c];
    }

    unsigned short* dst = tp + (size_t)b * KTOT + (size_t)(dbase + dsub * 8) * D2 + et * 4;
#pragma unroll
    for (int dl = 0; dl < 8; ++dl) {
        uint2 pp;
        pp.x = pack2bf16(acc[dl][0], acc[dl][1]);
        pp.y = pack2bf16(acc[dl][2], acc[dl][3]);
        *(uint2*)(dst + (size_t)dl * D2) = pp;
    }
}

// ---------------------------------------------------------------------------
// part[ks][64][1024] = tp[64, kchunk](bf16) @ W[1024, kchunk]^T.
// W is staged through LDS with WAVE-CONTIGUOUS global reads (each wave
// instruction reads 512B straight runs of a W row) to avoid the 256KB
// power-of-2 stride channel aliasing of direct fragment loads. fp32->bf16
// pack happens once during staging. Register prefetch of the next tile
// overlaps HBM latency with the MFMA phase.
__global__ __launch_bounds__(256, 4) void gemm_kernel(const unsigned short* __restrict__ tp,
                                                      const float* __restrict__ W,
                                                      float* __restrict__ part) {
    const int nt  = blockIdx.x;            // 0..15
    const int ks  = blockIdx.y;            // 0..KSPLIT-1
    const int w   = threadIdx.x >> 6;      // wave 0..3
    const int L   = threadIdx.x & 63;
    const int l16 = L & 15;
    const int lq  = L >> 4;                // 0..3 (k-quad)
    const int t   = threadIdx.x;
    const int ncol  = nt * 64 + w * 16;
    const int kbase = ks * KCHUNK;

    __shared__ unsigned short wlds[64][BK + WPAD];   // 64 x 144 bf16 = 18.4 KB

    // Staging map: idx = t + 256*i (i<8); row = idx>>5, c4 = idx&31 (float4 col).
    // A wave reads 2 rows x 512B contiguous per instruction.
    const int srow = t >> 5;          // base row for i=0; row(i) = srow + 8*i
    const int sc4  = t & 31;
    const float* wsrc = W + (size_t)(nt * 64 + srow) * KTOT + kbase + sc4 * 4;

    // A-fragments direct from tp (L1/L2-resident; identical across the 4 waves)
    const unsigned short* tpp = tp + (size_t)l16 * KTOT + kbase + lq * 8;

    f32x4 acc[4];
#pragma unroll
    for (int mt = 0; mt < 4; ++mt) acc[mt] = (f32x4){0.f, 0.f, 0.f, 0.f};

    // Prefetch tile 0
    float4 wreg[8];
#pragma unroll
    for (int i = 0; i < 8; ++i)
        wreg[i] = *(const float4*)(wsrc + (size_t)(8 * i) * KTOT);

    for (int bk = 0; bk < BKITERS; ++bk) {
        // Pack + write current tile to LDS
#pragma unroll
        for (int i = 0; i < 8; ++i) {
            uint2 pp;
            pp.x = pack2bf16(wreg[i].x, wreg[i].y);
            pp.y = pack2bf16(wreg[i].z, wreg[i].w);
            *(uint2*)&wlds[srow + 8 * i][sc4 * 4] = pp;
        }
        __syncthreads();   // tile bk visible

        // Issue prefetch for tile bk+1 (overlaps with MFMA phase)
        if (bk + 1 < BKITERS) {
            const float* wn = wsrc + (bk + 1) * BK;
#pragma unroll
            for (int i = 0; i < 8; ++i)
                wreg[i] = *(const float4*)(wn + (size_t)(8 * i) * KTOT);
        }

        // Compute: 4 mfma k-steps on tile bk
#pragma unroll
        for (int kk = 0; kk < KSTEPS; ++kk) {
            const int koff = bk * BK + kk * 32;
            bf16x8 a0 = *(const bf16x8*)(tpp + koff);
            bf16x8 a1 = *(const bf16x8*)(tpp + koff + 16 * KTOT);
            bf16x8 a2 = *(const bf16x8*)(tpp + koff + 32 * KTOT);
            bf16x8 a3 = *(const bf16x8*)(tpp + koff + 48 * KTOT);
            bf16x8 bw = *(const bf16x8*)&wlds[w * 16 + l16][kk * 32 + lq * 8];
            acc[0] = __builtin_amdgcn_mfma_f32_16x16x32_bf16(a0, bw, acc[0], 0, 0, 0);
            acc[1] = __builtin_amdgcn_mfma_f32_16x16x32_bf16(a1, bw, acc[1], 0, 0, 0);
            acc[2] = __builtin_amdgcn_mfma_f32_16x16x32_bf16(a2, bw, acc[2], 0, 0, 0);
            acc[3] = __builtin_amdgcn_mfma_f32_16x16x32_bf16(a3, bw, acc[3], 0, 0, 0);
        }
        __syncthreads();   // all reads of tile bk done before overwrite
    }

    // D[row = mt*16 + lq*4 + r][col = ncol + l16], one plain store each.
    float* pp = part + (size_t)ks * (B_DIM * NOUT) + ncol + l16;
#pragma unroll
    for (int mt = 0; mt < 4; ++mt)
#pragma unroll
        for (int r = 0; r < 4; ++r)
            pp[(size_t)(mt * 16 + lq * 4 + r) * NOUT] = acc[mt][r];
}

// ---------------------------------------------------------------------------
// out[m][n] = bias[n] + sum_ks part[ks][m][n].  16384 threads, float4 each.
__global__ __launch_bounds__(256) void reduce_kernel(const float* __restrict__ part,
                                                     const float* __restrict__ bias,
                                                     float* __restrict__ out) {
    const int i    = blockIdx.x * 256 + threadIdx.x;   // 0..16383
    const size_t o = (size_t)i * 4;
    const float* p = part + o;
    f32x4 a0 = {0.f, 0.f, 0.f, 0.f};
    f32x4 a1 = {0.f, 0.f, 0.f, 0.f};
#pragma unroll 8
    for (int ks = 0; ks < KSPLIT; ks += 2) {
        f32x4 x = *(const f32x4*)(p + (size_t)ks * (B_DIM * NOUT));
        f32x4 y = *(const f32x4*)(p + (size_t)(ks + 1) * (B_DIM * NOUT));
        a0 += x;
        a1 += y;
    }
    f32x4 bv = *(const f32x4*)(bias + (o & (NOUT - 1)));
    f32x4 r  = a0 + a1 + bv;
    *(f32x4*)(out + o) = r;
}

// ---------------------------------------------------------------------------
extern "C" void kernel_launch(void* const* d_in, const int* in_sizes, int n_in,
                              void* d_out, int out_size, void* d_ws, size_t ws_size,
                              hipStream_t stream) {
    const int*   fillers = (const int*)d_in[0];
    const int*   roles   = (const int*)d_in[1];
    const float* ftab    = (const float*)d_in[2];
    const float* rtab    = (const float*)d_in[3];
    const float* W       = (const float*)d_in[4];
    const float* bias    = (const float*)d_in[5];
    float* out = (float*)d_out;

    float*          part = (float*)d_ws;                       // 64*64*1024*4 = 16 MB
    unsigned short* tp   = (unsigned short*)((char*)d_ws + (size_t)KSPLIT * B_DIM * NOUT * 4);

    hipLaunchKernelGGL(tp_kernel, dim3(B_DIM, 8), dim3(256), 0, stream,
                       fillers, roles, ftab, rtab, tp);
    hipLaunchKernelGGL(gemm_kernel, dim3(16, KSPLIT), dim3(256), 0, stream, tp, W, part);
    hipLaunchKernelGGL(reduce_kernel, dim3(64), dim3(256), 0, stream, part, bias, out);
}